// Round 4
// baseline (27185.880 us; speedup 1.0000x reference)
//
#include <hip/hip_runtime.h>
#include <math.h>

// ---------------------------------------------------------------------------
// PhyRNN: 2-layer LSTM (B=64, T=3000, I=8, H=128) + FC head + double FD deriv.
//
// R4. History:
//  R1 16.6 ms: w[128]/thread, VGPR capped 128 -> spilled.
//  R2 36.5 ms: amdgpu_waves_per_eu(2,2) ignored; scratch storm (FETCH 6 GB).
//  R3 18.6 ms: launch_bounds(1024,4) is only a CAP; allocator chose 52/64
//              VGPRs chasing 8 waves/EU -> weights rematerialized from L2.
//  R4: force the allocator's hand via LDS: block LDS > 80 KB -> exactly 1
//      block/CU -> 512 thr = 8 waves = 2 waves/SIMD -> RA budget 256 VGPR.
//      512 threads, each owns TWO gate rows x K-half: w[2][64] = 128 regs
//      (~190 total, < 256 and < v255 encoding limit). Halving threads also
//      halves LDS h-broadcast traffic (each h float4 feeds 8 FMAs).
//      h_s halves offset by 80 dwords -> 2-addr reads hit disjoint bank quads.
//      Combine: shfl_xor(1) K-halves, shfl_xor(2) gate pairs; 1 barrier/step.
//
// Thread map: tid = j*4 + g2*2 + hf. Rows: ra = (2*g2)*128+j, rb = (2*g2+1)*128+j
// (g2=0 -> gates i,f ; g2=1 -> gates g,o). K-range [hf*64, hf*64+64).
//
// Precision: fp32 (no fp32 MFMA on CDNA4; double FD deriv amplifies noise).
// ws: h buffer 98.304 MB + y 0.768 MB + z 0.768 MB (fits, proven R1).
// ---------------------------------------------------------------------------

#define T_STEPS 3000
#define BATCH   64
#define HID     128
#define CHUNK   40      // 3000 = 75*40; xp_s = 40*512*4 = 80 KB -> 1 block/CU
#define HPAD    144     // h_s row: k<64 at [0..63], k>=64 at [80..143]
#define INV_DT  50.0f   // 1/0.02

__device__ __forceinline__ float sigmoid_(float x) {
    return 1.0f / (1.0f + __expf(-x));
}
__device__ __forceinline__ float tanh_(float x) {
    return 1.0f - 2.0f / (__expf(2.0f * x) + 1.0f);
}

// ---------------------------------------------------------------- layer 0 ---
__global__ void __launch_bounds__(512)
lstm_layer0(const float* __restrict__ x,      // [64][3000][8]
            const float* __restrict__ w_ih,   // [512][8]
            const float* __restrict__ w_hh,   // [512][128]
            const float* __restrict__ b_ih,
            const float* __restrict__ b_hh,
            float* __restrict__ h_out)        // [64][3000][128]
{
    const int b   = blockIdx.x;
    const int tid = threadIdx.x;
    const int j   = tid >> 2;            // hidden unit 0..127
    const int g2  = (tid >> 1) & 1;      // gate pair: 0={i,f} 1={g,o}
    const int hf  = tid & 1;             // K-half
    const int ra  = (2 * g2) * HID + j;
    const int rbr = (2 * g2 + 1) * HID + j;
    const int kb  = hf * 64;             // K base
    const int kp  = hf * 80;             // padded LDS base (disjoint bank quads)

    __shared__ __align__(16) float h_s[2][HPAD];
    __shared__ float pad0[21000];        // 84 KB: caps occupancy at 1 block/CU
    if (x == nullptr) {                  // never true; keeps pad0 allocated
        pad0[tid] = 1.0f;
        ((volatile float*)h_s)[0] = pad0[tid ^ 1];
    }

    // two weight rows (K-half each), register-resident: 128 VGPRs
    float wa[64], wb[64];
#pragma unroll
    for (int i = 0; i < 64; i += 4) {
        float4 va = *(const float4*)(w_hh + (size_t)ra  * HID + kb + i);
        float4 vb = *(const float4*)(w_hh + (size_t)rbr * HID + kb + i);
        wa[i] = va.x; wa[i+1] = va.y; wa[i+2] = va.z; wa[i+3] = va.w;
        wb[i] = vb.x; wb[i+1] = vb.y; wb[i+2] = vb.z; wb[i+3] = vb.w;
    }
    float wia[8], wib[8];
#pragma unroll
    for (int i = 0; i < 8; i += 4) {
        float4 va = *(const float4*)(w_ih + (size_t)ra  * 8 + i);
        float4 vb = *(const float4*)(w_ih + (size_t)rbr * 8 + i);
        wia[i] = va.x; wia[i+1] = va.y; wia[i+2] = va.z; wia[i+3] = va.w;
        wib[i] = vb.x; wib[i+1] = vb.y; wib[i+2] = vb.z; wib[i+3] = vb.w;
    }
    const float bia = b_ih[ra]  + b_hh[ra];
    const float bib = b_ih[rbr] + b_hh[rbr];
    float c = 0.0f;                      // valid in (tid&3)==0 threads

    if (tid < HPAD) h_s[0][tid] = 0.0f;  // zero incl. pad region
    __syncthreads();

    const float* xrow = x + (size_t)b * T_STEPS * 8;
    float* hb = h_out + (size_t)b * T_STEPS * HID;

#pragma unroll 1
    for (int t = 0; t < T_STEPS; ++t) {
        const int rb = t & 1;
        float4 xa = *(const float4*)(xrow + t * 8);
        float4 xc = *(const float4*)(xrow + t * 8 + 4);
        float xta = bia + wia[0]*xa.x + wia[1]*xa.y + wia[2]*xa.z + wia[3]*xa.w
                        + wia[4]*xc.x + wia[5]*xc.y + wia[6]*xc.z + wia[7]*xc.w;
        float xtb = bib + wib[0]*xa.x + wib[1]*xa.y + wib[2]*xa.z + wib[3]*xa.w
                        + wib[4]*xc.x + wib[5]*xc.y + wib[6]*xc.z + wib[7]*xc.w;

        float aa0 = 0.f, aa1 = 0.f, aa2 = 0.f, aa3 = 0.f;
        float ab0 = 0.f, ab1 = 0.f, ab2 = 0.f, ab3 = 0.f;
#pragma unroll
        for (int k4 = 0; k4 < 16; k4 += 4) {
            float4 h0 = *(const float4*)(&h_s[rb][kp + 4*k4]);
            float4 h1 = *(const float4*)(&h_s[rb][kp + 4*k4 + 4]);
            float4 h2 = *(const float4*)(&h_s[rb][kp + 4*k4 + 8]);
            float4 h3 = *(const float4*)(&h_s[rb][kp + 4*k4 + 12]);
            aa0 += wa[4*k4   ]*h0.x + wa[4*k4+ 1]*h0.y + wa[4*k4+ 2]*h0.z + wa[4*k4+ 3]*h0.w;
            ab0 += wb[4*k4   ]*h0.x + wb[4*k4+ 1]*h0.y + wb[4*k4+ 2]*h0.z + wb[4*k4+ 3]*h0.w;
            aa1 += wa[4*k4+ 4]*h1.x + wa[4*k4+ 5]*h1.y + wa[4*k4+ 6]*h1.z + wa[4*k4+ 7]*h1.w;
            ab1 += wb[4*k4+ 4]*h1.x + wb[4*k4+ 5]*h1.y + wb[4*k4+ 6]*h1.z + wb[4*k4+ 7]*h1.w;
            aa2 += wa[4*k4+ 8]*h2.x + wa[4*k4+ 9]*h2.y + wa[4*k4+10]*h2.z + wa[4*k4+11]*h2.w;
            ab2 += wb[4*k4+ 8]*h2.x + wb[4*k4+ 9]*h2.y + wb[4*k4+10]*h2.z + wb[4*k4+11]*h2.w;
            aa3 += wa[4*k4+12]*h3.x + wa[4*k4+13]*h3.y + wa[4*k4+14]*h3.z + wa[4*k4+15]*h3.w;
            ab3 += wb[4*k4+12]*h3.x + wb[4*k4+13]*h3.y + wb[4*k4+14]*h3.z + wb[4*k4+15]*h3.w;
        }
        float sa = (aa0 + aa1) + (aa2 + aa3);
        float sb = (ab0 + ab1) + (ab2 + ab3);
        sa += __shfl_xor(sa, 1);  sa += xta;     // K-half combine, then x-term
        sb += __shfl_xor(sb, 1);  sb += xtb;

        float acta = (g2 == 1) ? tanh_(sa) : sigmoid_(sa);  // g2=1: sa is gate g
        float actb = sigmoid_(sb);
        float oa = __shfl_xor(acta, 2);          // other pair's activated vals
        float ob = __shfl_xor(actb, 2);
        if ((tid & 3) == 0) {   // acta=sig_i actb=sig_f oa=tanh_g ob=sig_o
            c = actb * c + acta * oa;
            float h = ob * tanh_(c);
            h_s[rb ^ 1][j + ((j >> 6) << 4)] = h;
            hb[(size_t)t * HID + j] = h;
        }
        __syncthreads();
    }
}

// ---------------------------------------------------------------- layer 1 ---
// Per CHUNK=40: phase A (parallel) xp = bias + W_ih1 . h1 read from GLOBAL
// (L1-hot, 20 KB/chunk); phase B serial recurrence on h_s. h2 overwrites h1.
__global__ void __launch_bounds__(512)
lstm_layer1(const float* __restrict__ w_ih,   // [512][128]
            const float* __restrict__ w_hh,   // [512][128]
            const float* __restrict__ b_ih,
            const float* __restrict__ b_hh,
            float* __restrict__ h_buf)        // in: h1, out: h2 (in place)
{
    const int b   = blockIdx.x;
    const int tid = threadIdx.x;
    const int j   = tid >> 2;
    const int g2  = (tid >> 1) & 1;
    const int hf  = tid & 1;
    const int ra  = (2 * g2) * HID + j;
    const int rbr = (2 * g2 + 1) * HID + j;
    const int kb  = hf * 64;
    const int kp  = hf * 80;

    __shared__ __align__(16) float xp_s[CHUNK][512];   // 80 KB -> 1 block/CU
    __shared__ __align__(16) float h_s[2][HPAD];

    const float bia = b_ih[ra]  + b_hh[ra];
    const float bib = b_ih[rbr] + b_hh[rbr];
    float c = 0.0f;
    if (tid < HPAD) h_s[0][tid] = 0.0f;
    __syncthreads();

    float* hbB = h_buf + (size_t)b * T_STEPS * HID;
    float wa[64], wb[64];

    for (int t0 = 0; t0 < T_STEPS; t0 += CHUNK) {
        // ---- load W_ih half-rows (L2-resident)
#pragma unroll
        for (int i = 0; i < 64; i += 4) {
            float4 va = *(const float4*)(w_ih + (size_t)ra  * HID + kb + i);
            float4 vb = *(const float4*)(w_ih + (size_t)rbr * HID + kb + i);
            wa[i] = va.x; wa[i+1] = va.y; wa[i+2] = va.z; wa[i+3] = va.w;
            wb[i] = vb.x; wb[i+1] = vb.y; wb[i+2] = vb.z; wb[i+3] = vb.w;
        }
        // ---- phase A: xp_s[tau][j*4+g2*2+{0,1}] = bias + W_ih . h1[t0+tau]
#pragma unroll 2
        for (int tau = 0; tau < CHUNK; ++tau) {
            const float* hp_ = hbB + (size_t)(t0 + tau) * HID + kb;
            float aa0 = 0.f, aa1 = 0.f, aa2 = 0.f, aa3 = 0.f;
            float ab0 = 0.f, ab1 = 0.f, ab2 = 0.f, ab3 = 0.f;
#pragma unroll
            for (int k4 = 0; k4 < 16; k4 += 4) {
                float4 h0 = *(const float4*)(hp_ + 4*k4);
                float4 h1 = *(const float4*)(hp_ + 4*k4 + 4);
                float4 h2 = *(const float4*)(hp_ + 4*k4 + 8);
                float4 h3 = *(const float4*)(hp_ + 4*k4 + 12);
                aa0 += wa[4*k4   ]*h0.x + wa[4*k4+ 1]*h0.y + wa[4*k4+ 2]*h0.z + wa[4*k4+ 3]*h0.w;
                ab0 += wb[4*k4   ]*h0.x + wb[4*k4+ 1]*h0.y + wb[4*k4+ 2]*h0.z + wb[4*k4+ 3]*h0.w;
                aa1 += wa[4*k4+ 4]*h1.x + wa[4*k4+ 5]*h1.y + wa[4*k4+ 6]*h1.z + wa[4*k4+ 7]*h1.w;
                ab1 += wb[4*k4+ 4]*h1.x + wb[4*k4+ 5]*h1.y + wb[4*k4+ 6]*h1.z + wb[4*k4+ 7]*h1.w;
                aa2 += wa[4*k4+ 8]*h2.x + wa[4*k4+ 9]*h2.y + wa[4*k4+10]*h2.z + wa[4*k4+11]*h2.w;
                ab2 += wb[4*k4+ 8]*h2.x + wb[4*k4+ 9]*h2.y + wb[4*k4+10]*h2.z + wb[4*k4+11]*h2.w;
                aa3 += wa[4*k4+12]*h3.x + wa[4*k4+13]*h3.y + wa[4*k4+14]*h3.z + wa[4*k4+15]*h3.w;
                ab3 += wb[4*k4+12]*h3.x + wb[4*k4+13]*h3.y + wb[4*k4+14]*h3.z + wb[4*k4+15]*h3.w;
            }
            float sa = (aa0 + aa1) + (aa2 + aa3);
            float sb = (ab0 + ab1) + (ab2 + ab3);
            sa += __shfl_xor(sa, 1);
            sb += __shfl_xor(sb, 1);
            if (hf == 0) {
                *(float2*)&xp_s[tau][(j << 2) + (g2 << 1)] =
                    make_float2(bia + sa, bib + sb);
            }
        }
        // ---- swap to W_hh half-rows
#pragma unroll
        for (int i = 0; i < 64; i += 4) {
            float4 va = *(const float4*)(w_hh + (size_t)ra  * HID + kb + i);
            float4 vb = *(const float4*)(w_hh + (size_t)rbr * HID + kb + i);
            wa[i] = va.x; wa[i+1] = va.y; wa[i+2] = va.z; wa[i+3] = va.w;
            wb[i] = vb.x; wb[i+1] = vb.y; wb[i+2] = vb.z; wb[i+3] = vb.w;
        }
        __syncthreads();   // xp_s visible; all h1 chunk reads complete

        // ---- phase B: serial recurrence
#pragma unroll 1
        for (int tt = 0; tt < CHUNK; ++tt) {
            const int t  = t0 + tt;
            const int rb = t & 1;
            float2 xin = *(const float2*)&xp_s[tt][(j << 2) + (g2 << 1)];
            float aa0 = 0.f, aa1 = 0.f, aa2 = 0.f, aa3 = 0.f;
            float ab0 = 0.f, ab1 = 0.f, ab2 = 0.f, ab3 = 0.f;
#pragma unroll
            for (int k4 = 0; k4 < 16; k4 += 4) {
                float4 h0 = *(const float4*)(&h_s[rb][kp + 4*k4]);
                float4 h1 = *(const float4*)(&h_s[rb][kp + 4*k4 + 4]);
                float4 h2 = *(const float4*)(&h_s[rb][kp + 4*k4 + 8]);
                float4 h3 = *(const float4*)(&h_s[rb][kp + 4*k4 + 12]);
                aa0 += wa[4*k4   ]*h0.x + wa[4*k4+ 1]*h0.y + wa[4*k4+ 2]*h0.z + wa[4*k4+ 3]*h0.w;
                ab0 += wb[4*k4   ]*h0.x + wb[4*k4+ 1]*h0.y + wb[4*k4+ 2]*h0.z + wb[4*k4+ 3]*h0.w;
                aa1 += wa[4*k4+ 4]*h1.x + wa[4*k4+ 5]*h1.y + wa[4*k4+ 6]*h1.z + wa[4*k4+ 7]*h1.w;
                ab1 += wb[4*k4+ 4]*h1.x + wb[4*k4+ 5]*h1.y + wb[4*k4+ 6]*h1.z + wb[4*k4+ 7]*h1.w;
                aa2 += wa[4*k4+ 8]*h2.x + wa[4*k4+ 9]*h2.y + wa[4*k4+10]*h2.z + wa[4*k4+11]*h2.w;
                ab2 += wb[4*k4+ 8]*h2.x + wb[4*k4+ 9]*h2.y + wb[4*k4+10]*h2.z + wb[4*k4+11]*h2.w;
                aa3 += wa[4*k4+12]*h3.x + wa[4*k4+13]*h3.y + wa[4*k4+14]*h3.z + wa[4*k4+15]*h3.w;
                ab3 += wb[4*k4+12]*h3.x + wb[4*k4+13]*h3.y + wb[4*k4+14]*h3.z + wb[4*k4+15]*h3.w;
            }
            float sa = (aa0 + aa1) + (aa2 + aa3);
            float sb = (ab0 + ab1) + (ab2 + ab3);
            sa += __shfl_xor(sa, 1);  sa += xin.x;
            sb += __shfl_xor(sb, 1);  sb += xin.y;

            float acta = (g2 == 1) ? tanh_(sa) : sigmoid_(sa);
            float actb = sigmoid_(sb);
            float oa = __shfl_xor(acta, 2);
            float ob = __shfl_xor(actb, 2);
            if ((tid & 3) == 0) {
                c = actb * c + acta * oa;
                float h = ob * tanh_(c);
                h_s[rb ^ 1][j + ((j >> 6) << 4)] = h;
                hbB[(size_t)t * HID + j] = h;     // h2 overwrites h1
            }
            __syncthreads();
        }
    }
}

// ---------------------------------------------------------------- FC head ---
__global__ void __launch_bounds__(256)
fc_head(const float* __restrict__ h_buf,  // h2 [64][3000][128]
        const float* __restrict__ fc1_w, const float* __restrict__ fc1_b,
        const float* __restrict__ fc2_w, const float* __restrict__ fc2_b,
        const float* __restrict__ fc3_w, const float* __restrict__ fc3_b,
        float* __restrict__ y_bt)         // [64][3000]
{
    __shared__ __align__(16) float w1[16 * HID];   // 8 KB
    __shared__ float sb[89];
    const int tid = threadIdx.x;
    for (int i = tid; i < 16 * HID; i += 256) w1[i] = fc1_w[i];
    if (tid < 16) sb[tid]      = fc1_b[tid];
    if (tid < 64) sb[16 + tid] = fc2_w[tid];
    if (tid < 4)  sb[80 + tid] = fc2_b[tid];
    if (tid < 4)  sb[84 + tid] = fc3_w[tid];
    if (tid == 0) sb[88]       = fc3_b[0];
    __syncthreads();

    const int idx = blockIdx.x * 256 + tid;        // b*3000 + t
    if (idx >= BATCH * T_STEPS) return;
    const float* h = h_buf + (size_t)idx * HID;

    float y1[16];
#pragma unroll
    for (int jo = 0; jo < 16; ++jo) y1[jo] = sb[jo];
#pragma unroll 4
    for (int k4 = 0; k4 < 32; ++k4) {
        float4 hv = *(const float4*)(h + 4 * k4);
#pragma unroll
        for (int jo = 0; jo < 16; ++jo) {
            float4 wv = *(const float4*)(&w1[jo * HID + 4 * k4]);
            y1[jo] += wv.x*hv.x + wv.y*hv.y + wv.z*hv.z + wv.w*hv.w;
        }
    }
    float y2[4];
#pragma unroll
    for (int jo = 0; jo < 4; ++jo) {
        float a = sb[80 + jo];
#pragma unroll
        for (int k = 0; k < 16; ++k) a += sb[16 + jo * 16 + k] * fmaxf(y1[k], 0.0f);
        y2[jo] = fmaxf(a, 0.0f);
    }
    float y = sb[88];
#pragma unroll
    for (int k = 0; k < 4; ++k) y += sb[84 + k] * y2[k];

    y_bt[idx] = y;   // coalesced (t fast)
}

// ------------------------------------------------------------- FD stencil ---
__global__ void deriv_k(const float* __restrict__ in,   // [64][3000]
                        float* __restrict__ outp)       // [64][3000]
{
    const int idx = blockIdx.x * blockDim.x + threadIdx.x;
    if (idx >= BATCH * T_STEPS) return;
    const int t = idx % T_STEPS;
    float v;
    if (t == 0) {
        v = (-1.5f * in[idx] + 2.0f * in[idx + 1] - 0.5f * in[idx + 2]) * INV_DT;
    } else if (t == T_STEPS - 1) {
        v = (0.5f * in[idx - 2] - 2.0f * in[idx - 1] + 1.5f * in[idx]) * INV_DT;
    } else {
        v = (in[idx + 1] - in[idx - 1]) * (0.5f * INV_DT);
    }
    outp[idx] = v;
}

// ------------------------------------------------------------------ launch --
extern "C" void kernel_launch(void* const* d_in, const int* in_sizes, int n_in,
                              void* d_out, int out_size, void* d_ws, size_t ws_size,
                              hipStream_t stream)
{
    const float* x     = (const float*)d_in[0];
    const float* w_ih0 = (const float*)d_in[1];
    const float* w_hh0 = (const float*)d_in[2];
    const float* b_ih0 = (const float*)d_in[3];
    const float* b_hh0 = (const float*)d_in[4];
    const float* w_ih1 = (const float*)d_in[5];
    const float* w_hh1 = (const float*)d_in[6];
    const float* b_ih1 = (const float*)d_in[7];
    const float* b_hh1 = (const float*)d_in[8];
    const float* fc1_w = (const float*)d_in[9];
    const float* fc1_b = (const float*)d_in[10];
    const float* fc2_w = (const float*)d_in[11];
    const float* fc2_b = (const float*)d_in[12];
    const float* fc3_w = (const float*)d_in[13];
    const float* fc3_b = (const float*)d_in[14];
    float* out = (float*)d_out;

    // ws layout: h buffer (98.304 MB) | y (0.768 MB) | z (0.768 MB)
    float* h_buf = (float*)d_ws;
    float* y_bt  = (float*)((char*)d_ws + 98304000);
    float* z_bt  = (float*)((char*)d_ws + 98304000 + 768000);

    lstm_layer0<<<dim3(BATCH), dim3(512), 0, stream>>>(x, w_ih0, w_hh0, b_ih0, b_hh0, h_buf);
    lstm_layer1<<<dim3(BATCH), dim3(512), 0, stream>>>(w_ih1, w_hh1, b_ih1, b_hh1, h_buf);

    const int nelem = T_STEPS * BATCH;   // 192000 = 750 * 256
    fc_head<<<dim3(nelem / 256), dim3(256), 0, stream>>>(
        h_buf, fc1_w, fc1_b, fc2_w, fc2_b, fc3_w, fc3_b, y_bt);
    deriv_k<<<dim3(nelem / 256), dim3(256), 0, stream>>>(y_bt, z_bt);
    deriv_k<<<dim3(nelem / 256), dim3(256), 0, stream>>>(z_bt, out);
}